// Round 10
// baseline (472.230 us; speedup 1.0000x reference)
//
#include <hip/hip_runtime.h>

#define NB 2
#define NH 4
#define NS 512
#define ND 16
#define NF 32

typedef float v4f __attribute__((ext_vector_type(4)));

// ONE kernel: per-block private recompute of all projections (D=16 makes this
// cheap), then scores + softmax + PV + Wo. No workspace, no second dispatch.
// grid 512 = 8 bh x 64 q-tiles (8 qi each); 512 threads (8 waves); thread owns one k.
__global__ __launch_bounds__(512, 4) void k_all(
    const float* __restrict__ vin, const float* __restrict__ kin, const float* __restrict__ qin,
    const float* __restrict__ mask,
    const float* __restrict__ Wq, const float* __restrict__ bq,
    const float* __restrict__ Wk, const float* __restrict__ bk,
    const float* __restrict__ Wv, const float* __restrict__ bv,
    const float* __restrict__ Wo, const float* __restrict__ bo,
    const float* __restrict__ N1, const float* __restrict__ b1,
    const float* __restrict__ N2, const float* __restrict__ b2,
    float* __restrict__ attn, float* __restrict__ out)
{
    // ---- persistent LDS (63.0 KB total incl. union) ----
    __shared__ __align__(16) float vp_s[16 * 516];   // [d][s] transposed V'
    __shared__ __align__(16) float attn_s[8 * 516];  // [qi][k]
    __shared__ __align__(16) float hq_s[8 * 68];     // [qi][f 0..63]
    __shared__ float wo_s[256], bo_s[16], ov_s[128];
    __shared__ float redm[64], reds[64];             // [qi][wave]
    // staging region (weights/N1/qp/biases), reused as part_s after bC
    __shared__ __align__(16) float u_s[2304];
    float* N1_s = u_s;            // 1024  (32 x 32)
    float* Wq_s = u_s + 1024;     // 256
    float* Wk_s = u_s + 1280;     // 256
    float* Wv_s = u_s + 1536;     // 256
    float* qp_s = u_s + 1792;     // 8*17 = 136 (stride 17)
    float* bq_s = u_s + 1936;     // 16
    float* bk_s = u_s + 1952;     // 16
    float* bv_s = u_s + 1968;     // 16
    float* b1_s = u_s + 1984;     // 32 (byte off 7936, 16B-aligned)
    float* part_s = u_s;          // reuse: 128*17 = 2176 floats (phase >= 4)

    const int bh  = blockIdx.x >> 6;
    const int q0  = (blockIdx.x & 63) << 3;
    const int tid = threadIdx.x;
    const int wave = tid >> 6, lane = tid & 63;
    const int k = tid;
    const int r = bh * NS + k;

    // ---- issue per-thread global row loads early (hide latency) ----
    float4 kr4[4], vr4[4];
    {
        const float4* kg = (const float4*)(kin + (size_t)r * 16);
        const float4* vg = (const float4*)(vin + (size_t)r * 16);
#pragma unroll
        for (int j = 0; j < 4; ++j) { kr4[j] = kg[j]; vr4[j] = vg[j]; }
    }

    // ---- stage weights ----
    N1_s[tid]       = N1[tid];
    if (tid < 512 - 0) N1_s[tid + 512] = N1[tid + 512];
    if (tid < 256) { Wq_s[tid] = Wq[tid]; Wk_s[tid] = Wk[tid]; Wv_s[tid] = Wv[tid]; wo_s[tid] = Wo[tid]; }
    if (tid < 16)  { bq_s[tid] = bq[tid]; bk_s[tid] = bk[tid]; bv_s[tid] = bv[tid]; bo_s[tid] = bo[tid]; }
    if (tid < 32)  b1_s[tid] = b1[tid];
    __syncthreads();                                   // bA

    // ---- qp for the block's 8 q rows (threads 0..127) ----
    if (tid < 128) {
        const int qi = tid >> 4, e = tid & 15;
        const float* qrow = qin + (size_t)(bh * NS + q0 + qi) * 16;
        float acc = bq_s[e];
#pragma unroll
        for (int d = 0; d < 16; ++d) acc = fmaf(qrow[d], Wq_s[d * 16 + e], acc);
        qp_s[qi * 17 + e] = acc;
    }

    // ---- vp row (frees vr4 before hk) -> vp_s[d][k] ----
    {
        float vv[16];
#pragma unroll
        for (int j = 0; j < 4; ++j) {
            vv[4*j] = vr4[j].x; vv[4*j+1] = vr4[j].y; vv[4*j+2] = vr4[j].z; vv[4*j+3] = vr4[j].w;
        }
#pragma unroll
        for (int d = 0; d < 16; ++d) {
            float acc = bv_s[d];
#pragma unroll
            for (int e = 0; e < 16; ++e) acc = fmaf(vv[e], Wv_s[e * 16 + d], acc);
            vp_s[d * 516 + k] = acc;
        }
    }

    // ---- hk row in registers: kp then hkA/hkB' ----
    v4f hkA4[8], hkB4[8];
    {
        float kv[16];
#pragma unroll
        for (int j = 0; j < 4; ++j) {
            kv[4*j] = kr4[j].x; kv[4*j+1] = kr4[j].y; kv[4*j+2] = kr4[j].z; kv[4*j+3] = kr4[j].w;
        }
        float kp[16];
#pragma unroll
        for (int e = 0; e < 16; ++e) {
            float acc = bk_s[e];
#pragma unroll
            for (int d = 0; d < 16; ++d) acc = fmaf(kv[d], Wk_s[d * 16 + e], acc);
            kp[e] = acc;
        }
#pragma unroll
        for (int f4 = 0; f4 < 8; ++f4) { hkA4[f4] = 0.f; hkB4[f4] = *(const v4f*)&b1_s[f4 * 4]; }
#pragma unroll
        for (int e = 0; e < 16; ++e) {
            const float ke = kp[e];
#pragma unroll
            for (int f4 = 0; f4 < 8; ++f4) {
                hkA4[f4] += ke * *(const v4f*)&N1_s[e * 32 + f4 * 4];          // A = N1 rows 0..15
                hkB4[f4] += ke * *(const v4f*)&N1_s[(16 + e) * 32 + f4 * 4];   // B = N1 rows 16..31
            }
        }
    }
    __syncthreads();                                   // bB (qp_s ready)

    // ---- hq_s[qi][f]: one output per thread ----
    {
        const int qi = tid >> 6, f = tid & 63;
        const float* qpr = &qp_s[qi * 17];
        float acc;
        if (f < 32) {
            acc = 0.f;
#pragma unroll
            for (int d = 0; d < 16; ++d) acc = fmaf(qpr[d], N1_s[d * 32 + f], acc);
        } else {
            const int g = f - 32;
            acc = b1_s[g];
#pragma unroll
            for (int d = 0; d < 16; ++d) acc = fmaf(qpr[d], N1_s[(16 + d) * 32 + g], acc);
        }
        hq_s[qi * 68 + f] = acc;
    }

    // n2 (uniform -> scalar regs) + mask prefetch
    v4f n24[8];
#pragma unroll
    for (int f4 = 0; f4 < 8; ++f4)
        n24[f4] = (v4f){ N2[4*f4], N2[4*f4+1], N2[4*f4+2], N2[4*f4+3] };
    const float b2v = 2.0f * b2[0];
    const float* mbase = mask + (size_t)(bh >> 2) * NS * NS;   // H = 4
    float mreg[8];
#pragma unroll
    for (int qi = 0; qi < 8; ++qi) mreg[qi] = mbase[(size_t)(q0 + qi) * NS + k];
    __syncthreads();                                   // bC (hq_s, vp_s ready; u_s staging dead)

    // ---- phase 1: scores; per-wave max AND per-wave exp-sum ----
    float sreg[8];
#pragma unroll
    for (int qi = 0; qi < 8; ++qi) {
        const v4f* hq4 = (const v4f*)&hq_s[qi * 68];    // uniform -> LDS broadcast
        v4f acc = 0.f;
        const v4f z = 0.f;
#pragma unroll
        for (int f4 = 0; f4 < 8; ++f4) {
            v4f t1 = hq4[f4]     + hkB4[f4];            // A(q) + B'(k)
            v4f t2 = hq4[8 + f4] + hkA4[f4];            // B'(q) + A(k)
            v4f rr = __builtin_elementwise_max(t1, z) + __builtin_elementwise_max(t2, z);
            acc += n24[f4] * rr;
        }
        float s = (acc.x + acc.y) + (acc.z + acc.w) + b2v;
        s = fmaf(mreg[qi], -1e9f, s);

        float m = s;
#pragma unroll
        for (int off = 32; off > 0; off >>= 1) m = fmaxf(m, __shfl_xor(m, off));
        float e = __expf(s - m);
        sreg[qi] = s - m;
        float ss = e;
#pragma unroll
        for (int off = 32; off > 0; off >>= 1) ss += __shfl_xor(ss, off);
        if (lane == 0) { redm[qi * 8 + wave] = m; reds[qi * 8 + wave] = ss; }
    }
    __syncthreads();

    // ---- phase 2+3: block combine, normalize, write attn ----
#pragma unroll
    for (int qi = 0; qi < 8; ++qi) {
        float M = redm[qi * 8];
#pragma unroll
        for (int w = 1; w < 8; ++w) M = fmaxf(M, redm[qi * 8 + w]);
        float tot = 0.f;
#pragma unroll
        for (int w = 0; w < 8; ++w)
            tot = fmaf(reds[qi * 8 + w], __expf(redm[qi * 8 + w] - M), tot);
        float mw = redm[qi * 8 + wave];
        float p = __expf(sreg[qi] + (mw - M)) * __builtin_amdgcn_rcpf(tot);
        attn[(size_t)(bh * NS + q0 + qi) * NS + k] = p;
        attn_s[qi * 516 + k] = p;
    }
    __syncthreads();

    // ---- phase 4: PV from LDS. thread = (qi_p=tid&7, dgrp=(tid>>3)&3, koct=tid>>5) ----
    {
        const int qi_p = tid & 7;
        const int dgrp = (tid >> 3) & 3;
        const int koct = tid >> 5;                       // 0..15, 8 float4 each
        const float4* a4 = (const float4*)attn_s;        // row stride 129 float4
        const float4* v4 = (const float4*)vp_s;          // row stride 129 float4
        float acc0 = 0.f, acc1 = 0.f, acc2 = 0.f, acc3 = 0.f;
#pragma unroll
        for (int kq = 0; kq < 8; ++kq) {
            const int k4 = koct * 8 + kq;
            float4 av = a4[qi_p * 129 + k4];
            float4 w0 = v4[(dgrp * 4 + 0) * 129 + k4];
            float4 w1 = v4[(dgrp * 4 + 1) * 129 + k4];
            float4 w2 = v4[(dgrp * 4 + 2) * 129 + k4];
            float4 w3 = v4[(dgrp * 4 + 3) * 129 + k4];
            acc0 = fmaf(av.x, w0.x, fmaf(av.y, w0.y, fmaf(av.z, w0.z, fmaf(av.w, w0.w, acc0))));
            acc1 = fmaf(av.x, w1.x, fmaf(av.y, w1.y, fmaf(av.z, w1.z, fmaf(av.w, w1.w, acc1))));
            acc2 = fmaf(av.x, w2.x, fmaf(av.y, w2.y, fmaf(av.z, w2.z, fmaf(av.w, w2.w, acc2))));
            acc3 = fmaf(av.x, w3.x, fmaf(av.y, w3.y, fmaf(av.z, w3.z, fmaf(av.w, w3.w, acc3))));
        }
        part_s[(qi_p * 16 + dgrp * 4 + 0) * 17 + koct] = acc0;
        part_s[(qi_p * 16 + dgrp * 4 + 1) * 17 + koct] = acc1;
        part_s[(qi_p * 16 + dgrp * 4 + 2) * 17 + koct] = acc2;
        part_s[(qi_p * 16 + dgrp * 4 + 3) * 17 + koct] = acc3;
    }
    __syncthreads();

    // ---- phase 5: combine k-partials ----
    if (tid < 128) {
        float ov = 0.f;
#pragma unroll
        for (int kh = 0; kh < 16; ++kh) ov += part_s[tid * 17 + kh];
        ov_s[tid] = ov;
    }
    __syncthreads();

    // ---- phase 6: out = ov @ Wo + bo ----
    if (tid < 128) {
        const int qi2 = tid >> 4, d = tid & 15;
        float res = bo_s[d];
#pragma unroll
        for (int e = 0; e < 16; ++e)
            res = fmaf(ov_s[qi2 * 16 + e], wo_s[e * 16 + d], res);
        out[(size_t)(bh * NS + q0 + qi2) * 16 + d] = res;
    }
}

extern "C" void kernel_launch(void* const* d_in, const int* in_sizes, int n_in,
                              void* d_out, int out_size, void* d_ws, size_t ws_size,
                              hipStream_t stream)
{
    const float* v    = (const float*)d_in[0];
    const float* k    = (const float*)d_in[1];
    const float* q    = (const float*)d_in[2];
    const float* mask = (const float*)d_in[3];
    const float* Wq   = (const float*)d_in[4];
    const float* bq   = (const float*)d_in[5];
    const float* Wk   = (const float*)d_in[6];
    const float* bk   = (const float*)d_in[7];
    const float* Wv   = (const float*)d_in[8];
    const float* bv   = (const float*)d_in[9];
    const float* Wo   = (const float*)d_in[10];
    const float* bo   = (const float*)d_in[11];
    const float* N1   = (const float*)d_in[12];
    const float* b1   = (const float*)d_in[13];
    const float* N2   = (const float*)d_in[14];
    const float* b2   = (const float*)d_in[15];

    float* out  = (float*)d_out;                   // 65536 floats
    float* attn = out + (size_t)NB*NH*NS*ND;       // 2097152 floats

    k_all<<<512, 512, 0, stream>>>(v, k, q, mask, Wq, bq, Wk, bk, Wv, bv,
                                   Wo, bo, N1, b1, N2, b2, attn, out);
}

// Round 11
// 463.463 us; speedup vs baseline: 1.0189x; 1.0189x over previous
//
#include <hip/hip_runtime.h>

#define NB 2
#define NH 4
#define NS 512
#define ND 16
#define NF 32

typedef float v4f __attribute__((ext_vector_type(4)));

// ONE kernel: per-block private recompute of all projections (D=16 makes this
// cheap), then scores + softmax + PV + Wo. No workspace, no second dispatch.
// grid 512 = 8 bh x 64 q-tiles (8 qi each); 512 threads (8 waves); thread owns one k.
// launch_bounds (512,2): empirically (R10) the 2nd arg scales the VGPR cap as
// blocks/CU; 2 -> 128-VGPR cap. Live set ~110 -> no spills. LDS 62KB -> 2 blocks/CU.
__global__ __launch_bounds__(512, 2) void k_all(
    const float* __restrict__ vin, const float* __restrict__ kin, const float* __restrict__ qin,
    const float* __restrict__ mask,
    const float* __restrict__ Wq, const float* __restrict__ bq,
    const float* __restrict__ Wk, const float* __restrict__ bk,
    const float* __restrict__ Wv, const float* __restrict__ bv,
    const float* __restrict__ Wo, const float* __restrict__ bo,
    const float* __restrict__ N1, const float* __restrict__ b1,
    const float* __restrict__ N2, const float* __restrict__ b2,
    float* __restrict__ attn, float* __restrict__ out)
{
    // ---- persistent LDS (~62 KB) ----
    __shared__ __align__(16) float vp_s[16 * 516];   // [d][s] transposed V'
    __shared__ __align__(16) float attn_s[8 * 516];  // [qi][k]
    __shared__ __align__(16) float hq_s[8 * 68];     // [qi][f 0..63]
    __shared__ float wo_s[256], bo_s[16], ov_s[128];
    __shared__ float redm[64], reds[64];             // [qi][wave]
    // staging region (weights/N1/qp/biases), reused as part_s after bC
    __shared__ __align__(16) float u_s[2304];
    float* N1_s = u_s;            // 1024  (32 x 32)
    float* Wq_s = u_s + 1024;     // 256
    float* Wk_s = u_s + 1280;     // 256
    float* Wv_s = u_s + 1536;     // 256
    float* qp_s = u_s + 1792;     // 8*17 = 136 (stride 17)
    float* bq_s = u_s + 1936;     // 16
    float* bk_s = u_s + 1952;     // 16
    float* bv_s = u_s + 1968;     // 16
    float* b1_s = u_s + 1984;     // 32 (byte off 7936, 16B-aligned)
    float* part_s = u_s;          // reuse: 128*17 = 2176 floats (phase >= 4)

    const int bh  = blockIdx.x >> 6;
    const int q0  = (blockIdx.x & 63) << 3;
    const int tid = threadIdx.x;
    const int wave = tid >> 6, lane = tid & 63;
    const int k = tid;
    const int r = bh * NS + k;

    // ---- issue per-thread global row loads early (hide latency) ----
    float4 kr4[4], vr4[4];
    {
        const float4* kg = (const float4*)(kin + (size_t)r * 16);
        const float4* vg = (const float4*)(vin + (size_t)r * 16);
#pragma unroll
        for (int j = 0; j < 4; ++j) { kr4[j] = kg[j]; vr4[j] = vg[j]; }
    }

    // ---- stage weights ----
    N1_s[tid]       = N1[tid];
    N1_s[tid + 512] = N1[tid + 512];
    if (tid < 256) { Wq_s[tid] = Wq[tid]; Wk_s[tid] = Wk[tid]; Wv_s[tid] = Wv[tid]; wo_s[tid] = Wo[tid]; }
    if (tid < 16)  { bq_s[tid] = bq[tid]; bk_s[tid] = bk[tid]; bv_s[tid] = bv[tid]; bo_s[tid] = bo[tid]; }
    if (tid < 32)  b1_s[tid] = b1[tid];
    __syncthreads();                                   // bA

    // ---- qp for the block's 8 q rows (threads 0..127) ----
    if (tid < 128) {
        const int qi = tid >> 4, e = tid & 15;
        const float* qrow = qin + (size_t)(bh * NS + q0 + qi) * 16;
        float acc = bq_s[e];
#pragma unroll
        for (int d = 0; d < 16; ++d) acc = fmaf(qrow[d], Wq_s[d * 16 + e], acc);
        qp_s[qi * 17 + e] = acc;
    }

    // ---- vp row (frees vr4 before hk) -> vp_s[d][k] ----
    {
        float vv[16];
#pragma unroll
        for (int j = 0; j < 4; ++j) {
            vv[4*j] = vr4[j].x; vv[4*j+1] = vr4[j].y; vv[4*j+2] = vr4[j].z; vv[4*j+3] = vr4[j].w;
        }
#pragma unroll
        for (int d = 0; d < 16; ++d) {
            float acc = bv_s[d];
#pragma unroll
            for (int e = 0; e < 16; ++e) acc = fmaf(vv[e], Wv_s[e * 16 + d], acc);
            vp_s[d * 516 + k] = acc;
        }
    }

    // ---- hk row in registers: kp then hkA/hkB' ----
    v4f hkA4[8], hkB4[8];
    {
        float kv[16];
#pragma unroll
        for (int j = 0; j < 4; ++j) {
            kv[4*j] = kr4[j].x; kv[4*j+1] = kr4[j].y; kv[4*j+2] = kr4[j].z; kv[4*j+3] = kr4[j].w;
        }
        float kp[16];
#pragma unroll
        for (int e = 0; e < 16; ++e) {
            float acc = bk_s[e];
#pragma unroll
            for (int d = 0; d < 16; ++d) acc = fmaf(kv[d], Wk_s[d * 16 + e], acc);
            kp[e] = acc;
        }
#pragma unroll
        for (int f4 = 0; f4 < 8; ++f4) { hkA4[f4] = 0.f; hkB4[f4] = *(const v4f*)&b1_s[f4 * 4]; }
#pragma unroll
        for (int e = 0; e < 16; ++e) {
            const float ke = kp[e];
#pragma unroll
            for (int f4 = 0; f4 < 8; ++f4) {
                hkA4[f4] += ke * *(const v4f*)&N1_s[e * 32 + f4 * 4];          // A = N1 rows 0..15
                hkB4[f4] += ke * *(const v4f*)&N1_s[(16 + e) * 32 + f4 * 4];   // B = N1 rows 16..31
            }
        }
    }
    __syncthreads();                                   // bB (qp_s ready)

    // ---- hq_s[qi][f]: one output per thread ----
    {
        const int qi = tid >> 6, f = tid & 63;
        const float* qpr = &qp_s[qi * 17];
        float acc;
        if (f < 32) {
            acc = 0.f;
#pragma unroll
            for (int d = 0; d < 16; ++d) acc = fmaf(qpr[d], N1_s[d * 32 + f], acc);
        } else {
            const int g = f - 32;
            acc = b1_s[g];
#pragma unroll
            for (int d = 0; d < 16; ++d) acc = fmaf(qpr[d], N1_s[(16 + d) * 32 + g], acc);
        }
        hq_s[qi * 68 + f] = acc;
    }

    // n2 as UNIFORM scalars (s_load -> SGPRs; used as the one-SGPR operand of each fma)
    float n2s[32];
#pragma unroll
    for (int f = 0; f < 32; ++f) n2s[f] = N2[f];
    const float b2v = 2.0f * b2[0];
    const float* mbase = mask + (size_t)(bh >> 2) * NS * NS;   // H = 4
    float mreg[8];
#pragma unroll
    for (int qi = 0; qi < 8; ++qi) mreg[qi] = mbase[(size_t)(q0 + qi) * NS + k];
    __syncthreads();                                   // bC (hq_s, vp_s ready; u_s staging dead)

    // ---- phase 1: scores; per-wave max AND per-wave exp-sum ----
    float sreg[8];
#pragma unroll
    for (int qi = 0; qi < 8; ++qi) {
        const v4f* hq4 = (const v4f*)&hq_s[qi * 68];    // uniform -> LDS broadcast
        const v4f z = 0.f;
        float a0 = 0.f, a1 = 0.f, a2 = 0.f, a3 = 0.f;
#pragma unroll
        for (int f4 = 0; f4 < 8; ++f4) {
            v4f t1 = hq4[f4]     + hkB4[f4];            // A(q) + B'(k)
            v4f t2 = hq4[8 + f4] + hkA4[f4];            // B'(q) + A(k)
            v4f rr = __builtin_elementwise_max(t1, z) + __builtin_elementwise_max(t2, z);
            a0 = fmaf(n2s[4*f4    ], rr.x, a0);
            a1 = fmaf(n2s[4*f4 + 1], rr.y, a1);
            a2 = fmaf(n2s[4*f4 + 2], rr.z, a2);
            a3 = fmaf(n2s[4*f4 + 3], rr.w, a3);
        }
        float s = (a0 + a1) + (a2 + a3) + b2v;
        s = fmaf(mreg[qi], -1e9f, s);

        float m = s;
#pragma unroll
        for (int off = 32; off > 0; off >>= 1) m = fmaxf(m, __shfl_xor(m, off));
        float e = __expf(s - m);
        sreg[qi] = s - m;
        float ss = e;
#pragma unroll
        for (int off = 32; off > 0; off >>= 1) ss += __shfl_xor(ss, off);
        if (lane == 0) { redm[qi * 8 + wave] = m; reds[qi * 8 + wave] = ss; }
    }
    __syncthreads();

    // ---- phase 2+3: block combine, normalize, write attn ----
#pragma unroll
    for (int qi = 0; qi < 8; ++qi) {
        float M = redm[qi * 8];
#pragma unroll
        for (int w = 1; w < 8; ++w) M = fmaxf(M, redm[qi * 8 + w]);
        float tot = 0.f;
#pragma unroll
        for (int w = 0; w < 8; ++w)
            tot = fmaf(reds[qi * 8 + w], __expf(redm[qi * 8 + w] - M), tot);
        float mw = redm[qi * 8 + wave];
        float p = __expf(sreg[qi] + (mw - M)) * __builtin_amdgcn_rcpf(tot);
        attn[(size_t)(bh * NS + q0 + qi) * NS + k] = p;
        attn_s[qi * 516 + k] = p;
    }
    __syncthreads();

    // ---- phase 4: PV from LDS. thread = (qi_p=tid&7, dgrp=(tid>>3)&3, koct=tid>>5) ----
    {
        const int qi_p = tid & 7;
        const int dgrp = (tid >> 3) & 3;
        const int koct = tid >> 5;                       // 0..15, 8 float4 each
        const float4* a4 = (const float4*)attn_s;        // row stride 129 float4
        const float4* v4 = (const float4*)vp_s;          // row stride 129 float4
        float acc0 = 0.f, acc1 = 0.f, acc2 = 0.f, acc3 = 0.f;
#pragma unroll
        for (int kq = 0; kq < 8; ++kq) {
            const int k4 = koct * 8 + kq;
            float4 av = a4[qi_p * 129 + k4];
            float4 w0 = v4[(dgrp * 4 + 0) * 129 + k4];
            float4 w1 = v4[(dgrp * 4 + 1) * 129 + k4];
            float4 w2 = v4[(dgrp * 4 + 2) * 129 + k4];
            float4 w3 = v4[(dgrp * 4 + 3) * 129 + k4];
            acc0 = fmaf(av.x, w0.x, fmaf(av.y, w0.y, fmaf(av.z, w0.z, fmaf(av.w, w0.w, acc0))));
            acc1 = fmaf(av.x, w1.x, fmaf(av.y, w1.y, fmaf(av.z, w1.z, fmaf(av.w, w1.w, acc1))));
            acc2 = fmaf(av.x, w2.x, fmaf(av.y, w2.y, fmaf(av.z, w2.z, fmaf(av.w, w2.w, acc2))));
            acc3 = fmaf(av.x, w3.x, fmaf(av.y, w3.y, fmaf(av.z, w3.z, fmaf(av.w, w3.w, acc3))));
        }
        part_s[(qi_p * 16 + dgrp * 4 + 0) * 17 + koct] = acc0;
        part_s[(qi_p * 16 + dgrp * 4 + 1) * 17 + koct] = acc1;
        part_s[(qi_p * 16 + dgrp * 4 + 2) * 17 + koct] = acc2;
        part_s[(qi_p * 16 + dgrp * 4 + 3) * 17 + koct] = acc3;
    }
    __syncthreads();

    // ---- phase 5: combine k-partials ----
    if (tid < 128) {
        float ov = 0.f;
#pragma unroll
        for (int kh = 0; kh < 16; ++kh) ov += part_s[tid * 17 + kh];
        ov_s[tid] = ov;
    }
    __syncthreads();

    // ---- phase 6: out = ov @ Wo + bo ----
    if (tid < 128) {
        const int qi2 = tid >> 4, d = tid & 15;
        float res = bo_s[d];
#pragma unroll
        for (int e = 0; e < 16; ++e)
            res = fmaf(ov_s[qi2 * 16 + e], wo_s[e * 16 + d], res);
        out[(size_t)(bh * NS + q0 + qi2) * 16 + d] = res;
    }
}

extern "C" void kernel_launch(void* const* d_in, const int* in_sizes, int n_in,
                              void* d_out, int out_size, void* d_ws, size_t ws_size,
                              hipStream_t stream)
{
    const float* v    = (const float*)d_in[0];
    const float* k    = (const float*)d_in[1];
    const float* q    = (const float*)d_in[2];
    const float* mask = (const float*)d_in[3];
    const float* Wq   = (const float*)d_in[4];
    const float* bq   = (const float*)d_in[5];
    const float* Wk   = (const float*)d_in[6];
    const float* bk   = (const float*)d_in[7];
    const float* Wv   = (const float*)d_in[8];
    const float* bv   = (const float*)d_in[9];
    const float* Wo   = (const float*)d_in[10];
    const float* bo   = (const float*)d_in[11];
    const float* N1   = (const float*)d_in[12];
    const float* b1   = (const float*)d_in[13];
    const float* N2   = (const float*)d_in[14];
    const float* b2   = (const float*)d_in[15];

    float* out  = (float*)d_out;                   // 65536 floats
    float* attn = out + (size_t)NB*NH*NS*ND;       // 2097152 floats

    k_all<<<512, 512, 0, stream>>>(v, k, q, mask, Wq, bq, Wk, bk, Wv, bv,
                                   Wo, bo, N1, b1, N2, b2, attn, out);
}

// Round 12
// 32.396 us; speedup vs baseline: 14.5769x; 14.3063x over previous
//
#include <hip/hip_runtime.h>

#define NB 2
#define NH 4
#define NS 512
#define ND 16
#define NF 32

typedef float v4f __attribute__((ext_vector_type(4)));

// workspace layouts:
//   hq_rm : [bh][s 0..511][f 0..63]  row-major (f<32: @A, f>=32: @B+b1) -- float4-aligned rows
//   hkp   : [bh][half(A=0,B=1)][f4 0..7][s 0..511][c 0..3]  paired-x4
//   vpt   : [bh][d 0..15][s 0..511]

// ---------------- Kernel 1: fused projections ----------------
// grid 80 = 8 bh * 2 s-chunks * 5 jobs; 256 threads.
// job 0/1: hq A/B half (row-major via LDS transpose); 2/3: hk A/B (paired-x4 via LDS transpose); 4: vpt.
__global__ __launch_bounds__(256) void k_proj(
    const float* __restrict__ q, const float* __restrict__ kin, const float* __restrict__ v,
    const float* __restrict__ Wq, const float* __restrict__ bq,
    const float* __restrict__ Wk, const float* __restrict__ bk,
    const float* __restrict__ Wv, const float* __restrict__ bv,
    const float* __restrict__ N1, const float* __restrict__ b1,
    float* __restrict__ hq_rm, float* __restrict__ hkp, float* __restrict__ vpt)
{
    __shared__ float m_s[16 * 32];
    __shared__ float c_s[32];
    __shared__ float trans_s[256 * 33];   // [s_loc][f 0..31]

    const int bid = blockIdx.x;
    const int job = bid % 5;
    const int sc  = (bid / 5) & 1;
    const int bh  = bid / 10;
    const int t   = threadIdx.x;

    const float* W    = (job < 2) ? Wq : (job < 4 ? Wk : Wv);
    const float* bias = (job < 2) ? bq : (job < 4 ? bk : bv);
    const float* x    = (job < 2) ? q  : (job < 4 ? kin : v);

    if (job < 4) {
        const int noff = (job & 1) * 16;
        for (int i = t; i < 512; i += 256) {
            int e = i >> 5, f = i & 31;
            float m = 0.f;
#pragma unroll
            for (int d = 0; d < 16; ++d)
                m = fmaf(W[e * 16 + d], N1[(noff + d) * 32 + f], m);
            m_s[i] = m;
        }
        if (t < 32) {
            float c = (job & 1) ? b1[t] : 0.f;
#pragma unroll
            for (int d = 0; d < 16; ++d)
                c = fmaf(bias[d], N1[(noff + d) * 32 + t], c);
            c_s[t] = c;
        }
    } else {
        int e = t >> 4, d = t & 15;
        m_s[e * 32 + d] = W[e * 16 + d];
        if (t < 16) c_s[t] = bias[t];
    }
    __syncthreads();

    const int s = sc * 256 + t;
    const int r = bh * NS + s;

    float xv[16];
    const float4* x4 = (const float4*)(x + (size_t)r * 16);
#pragma unroll
    for (int j = 0; j < 4; ++j) {
        float4 a = x4[j];
        xv[4*j] = a.x; xv[4*j+1] = a.y; xv[4*j+2] = a.z; xv[4*j+3] = a.w;
    }

    if (job < 4) {
        float h[32];
#pragma unroll
        for (int f = 0; f < 32; ++f) h[f] = c_s[f];
#pragma unroll
        for (int e = 0; e < 16; ++e)
#pragma unroll
            for (int f = 0; f < 32; ++f)
                h[f] = fmaf(xv[e], m_s[e * 32 + f], h[f]);
#pragma unroll
        for (int f = 0; f < 32; ++f) trans_s[t * 33 + f] = h[f];
        __syncthreads();

        if (job < 2) {
            // hq row-major: row s, half (job&1)
            float* outb = hq_rm + (((size_t)(bh * NS + sc * 256)) << 6) + (job & 1) * 32;
#pragma unroll
            for (int it = 0; it < 32; ++it) {
                int j = it * 256 + t;            // 0..8191 = 256 s x 32 f
                int sl = j >> 5, f = j & 31;
                outb[((size_t)sl << 6) + f] = trans_s[sl * 33 + f];
            }
        } else {
            // hk paired-x4: [half][f4][s][c]
            float* outb = hkp + (size_t)bh * 32768 + (size_t)(job & 1) * 16384 + sc * 1024;
#pragma unroll
            for (int it = 0; it < 32; ++it) {
                int i = it * 256 + t;            // 0..8191 = 8 f4 x 256 s x 4 c
                int f4 = i >> 10, rem = i & 1023;
                int sl = rem >> 2, c = rem & 3;
                outb[(size_t)f4 * 2048 + rem] = trans_s[sl * 33 + f4 * 4 + c];
            }
        }
    } else {
        float* outb = vpt + (size_t)bh * 8192;
        float h[16];
#pragma unroll
        for (int d = 0; d < 16; ++d) h[d] = c_s[d];
#pragma unroll
        for (int e = 0; e < 16; ++e)
#pragma unroll
            for (int d = 0; d < 16; ++d)
                h[d] = fmaf(xv[e], m_s[e * 32 + d], h[d]);
#pragma unroll
        for (int d = 0; d < 16; ++d)
            outb[(size_t)d * NS + s] = h[d];
    }
}

// ---------------- Kernel 2: fused scores + softmax + PV + Wo ----------------
// grid 512 = 8 bh x 64 q-tiles (8 qi); 512 threads (8 waves); thread owns one k.
// NO min-waves in launch_bounds: let the compiler allocate VGPRs freely
// (R10/R11 evidence: min-waves=4 caps at 64 VGPR, =2 at 128 -> wholesale spilling).
__global__ __launch_bounds__(512) void k_fused(
    const float* __restrict__ hq_rm, const float* __restrict__ hkp,
    const float* __restrict__ vpt,
    const float* __restrict__ N2, const float* __restrict__ b2,
    const float* __restrict__ mask,
    const float* __restrict__ Wo, const float* __restrict__ bo,
    float* __restrict__ attn, float* __restrict__ out)
{
    __shared__ __align__(16) float attn_s[8 * 516];  // [qi][k]
    __shared__ float wo_s[256];
    __shared__ float bo_s[16];
    __shared__ float ov_s[128];                      // [qi][d]
    __shared__ float part_s[128 * 17];               // [qi*16+d][koct]
    __shared__ float redm[64];                       // [qi][wave] max
    __shared__ float reds[64];                       // [qi][wave] sum(exp(s-m_w))

    const int bh  = blockIdx.x >> 6;
    const int q0  = (blockIdx.x & 63) << 3;
    const int tid = threadIdx.x;
    const int wave = tid >> 6, lane = tid & 63;
    const int k = tid;
    const size_t base = (size_t)bh * 32768;

    // ---- per-thread hk fragments: 16 coalesced float4 loads ----
    v4f hkA4[8], hkB4[8];
    const v4f* hkb = (const v4f*)(hkp + base + (size_t)k * 4);   // stride per f4 = 2048 floats = 512 v4f
#pragma unroll
    for (int f4 = 0; f4 < 8; ++f4) hkA4[f4] = hkb[f4 * 512];
#pragma unroll
    for (int f4 = 0; f4 < 8; ++f4) hkB4[f4] = hkb[4096 + f4 * 512];

    // n2 as uniform (scalar) values packed to v4f
    v4f n24[8];
#pragma unroll
    for (int f4 = 0; f4 < 8; ++f4)
        n24[f4] = (v4f){ N2[4*f4], N2[4*f4+1], N2[4*f4+2], N2[4*f4+3] };
    const float b2v = 2.0f * b2[0];

    // mask prefetch (8 rows)
    const float* mbase = mask + (size_t)(bh >> 2) * NS * NS;   // H=4
    float mreg[8];
#pragma unroll
    for (int qi = 0; qi < 8; ++qi) mreg[qi] = mbase[(size_t)(q0 + qi) * NS + k];

    if (tid < 256) wo_s[tid] = Wo[tid];
    if (tid < 16)  bo_s[tid] = bo[tid];
    __syncthreads();

    // ---- phase 1: scores; per-wave max AND per-wave exp-sum ----
    float sreg[8];   // s - m_w (wave-shifted)
#pragma unroll
    for (int qi = 0; qi < 8; ++qi) {
        const v4f* hq4 = (const v4f*)(hq_rm + (((size_t)(bh * NS + q0 + qi)) << 6)); // uniform -> s_load
        v4f acc = 0.f;
        const v4f z = 0.f;
#pragma unroll
        for (int f4 = 0; f4 < 8; ++f4) {
            v4f t1 = hq4[f4]     + hkB4[f4];   // A(q) + B'(k)
            v4f t2 = hq4[8 + f4] + hkA4[f4];   // B'(q) + A(k)
            v4f rr = __builtin_elementwise_max(t1, z) + __builtin_elementwise_max(t2, z);
            acc += n24[f4] * rr;
        }
        float s = (acc.x + acc.y) + (acc.z + acc.w) + b2v;
        s = fmaf(mreg[qi], -1e9f, s);

        float m = s;
#pragma unroll
        for (int off = 32; off > 0; off >>= 1) m = fmaxf(m, __shfl_xor(m, off));
        float e = __expf(s - m);
        sreg[qi] = s - m;
        float ss = e;
#pragma unroll
        for (int off = 32; off > 0; off >>= 1) ss += __shfl_xor(ss, off);
        if (lane == 0) { redm[qi * 8 + wave] = m; reds[qi * 8 + wave] = ss; }
    }
    __syncthreads();

    // ---- phase 2+3: block combine, normalize, write attn ----
#pragma unroll
    for (int qi = 0; qi < 8; ++qi) {
        float M = redm[qi * 8];
#pragma unroll
        for (int w = 1; w < 8; ++w) M = fmaxf(M, redm[qi * 8 + w]);
        float tot = 0.f;
#pragma unroll
        for (int w = 0; w < 8; ++w)
            tot = fmaf(reds[qi * 8 + w], __expf(redm[qi * 8 + w] - M), tot);
        float mw = redm[qi * 8 + wave];
        float p = __expf(sreg[qi] + (mw - M)) * __builtin_amdgcn_rcpf(tot);
        attn[(size_t)(bh * NS + q0 + qi) * NS + k] = p;
        attn_s[qi * 516 + k] = p;
    }
    __syncthreads();

    // ---- phase 4: PV. thread = (qi_p = tid&7, dgrp = (tid>>3)&3, koct = tid>>5) ----
    {
        const int qi_p = tid & 7;
        const int dgrp = (tid >> 3) & 3;
        const int koct = tid >> 5;                          // 0..15, 8 float4 each
        const float4* a4 = (const float4*)attn_s;           // row stride 129
        const float4* v4 = (const float4*)(vpt + (size_t)bh * 8192); // [d][128]
        float acc0 = 0.f, acc1 = 0.f, acc2 = 0.f, acc3 = 0.f;
#pragma unroll
        for (int kq = 0; kq < 8; ++kq) {
            const int k4 = koct * 8 + kq;
            float4 av = a4[qi_p * 129 + k4];
            float4 w0 = v4[(dgrp * 4 + 0) * 128 + k4];
            float4 w1 = v4[(dgrp * 4 + 1) * 128 + k4];
            float4 w2 = v4[(dgrp * 4 + 2) * 128 + k4];
            float4 w3 = v4[(dgrp * 4 + 3) * 128 + k4];
            acc0 = fmaf(av.x, w0.x, fmaf(av.y, w0.y, fmaf(av.z, w0.z, fmaf(av.w, w0.w, acc0))));
            acc1 = fmaf(av.x, w1.x, fmaf(av.y, w1.y, fmaf(av.z, w1.z, fmaf(av.w, w1.w, acc1))));
            acc2 = fmaf(av.x, w2.x, fmaf(av.y, w2.y, fmaf(av.z, w2.z, fmaf(av.w, w2.w, acc2))));
            acc3 = fmaf(av.x, w3.x, fmaf(av.y, w3.y, fmaf(av.z, w3.z, fmaf(av.w, w3.w, acc3))));
        }
        part_s[(qi_p * 16 + dgrp * 4 + 0) * 17 + koct] = acc0;
        part_s[(qi_p * 16 + dgrp * 4 + 1) * 17 + koct] = acc1;
        part_s[(qi_p * 16 + dgrp * 4 + 2) * 17 + koct] = acc2;
        part_s[(qi_p * 16 + dgrp * 4 + 3) * 17 + koct] = acc3;
    }
    __syncthreads();

    // ---- phase 5: combine k-partials ----
    if (tid < 128) {
        float ov = 0.f;
#pragma unroll
        for (int kh = 0; kh < 16; ++kh) ov += part_s[tid * 17 + kh];
        ov_s[tid] = ov;
    }
    __syncthreads();

    // ---- phase 6: out = ov @ Wo + bo ----
    if (tid < 128) {
        const int qi2 = tid >> 4, d = tid & 15;
        float res = bo_s[d];
#pragma unroll
        for (int e = 0; e < 16; ++e)
            res = fmaf(ov_s[qi2 * 16 + e], wo_s[e * 16 + d], res);
        out[(size_t)(bh * NS + q0 + qi2) * 16 + d] = res;
    }
}

extern "C" void kernel_launch(void* const* d_in, const int* in_sizes, int n_in,
                              void* d_out, int out_size, void* d_ws, size_t ws_size,
                              hipStream_t stream)
{
    const float* v    = (const float*)d_in[0];
    const float* k    = (const float*)d_in[1];
    const float* q    = (const float*)d_in[2];
    const float* mask = (const float*)d_in[3];
    const float* Wq   = (const float*)d_in[4];
    const float* bq   = (const float*)d_in[5];
    const float* Wk   = (const float*)d_in[6];
    const float* bk   = (const float*)d_in[7];
    const float* Wv   = (const float*)d_in[8];
    const float* bv   = (const float*)d_in[9];
    const float* Wo   = (const float*)d_in[10];
    const float* bo   = (const float*)d_in[11];
    const float* N1   = (const float*)d_in[12];
    const float* b1   = (const float*)d_in[13];
    const float* N2   = (const float*)d_in[14];
    const float* b2   = (const float*)d_in[15];

    float* out  = (float*)d_out;                   // 65536 floats
    float* attn = out + (size_t)NB*NH*NS*ND;       // 2097152 floats

    float* hq_rm = (float*)d_ws;                   // 262144 floats
    float* hkp   = hq_rm + (size_t)8 * 32768;      // 262144 floats
    float* vpt   = hkp + (size_t)8 * 32768;        // 65536 floats

    k_proj <<<80, 256, 0, stream>>>(q, k, v, Wq, bq, Wk, bk, Wv, bv, N1, b1, hq_rm, hkp, vpt);
    k_fused<<<512, 512, 0, stream>>>(hq_rm, hkp, vpt, N2, b2, mask, Wo, bo, attn, out);
}